// Round 1
// baseline (592.827 us; speedup 1.0000x reference)
//
#include <hip/hip_runtime.h>

// Spiking LIF forward scan, LDS-staged + fully non-temporal global access.
//
// x: (B=128, C=512, T=1024) fp32, t contiguous. beta scalar, Vth per channel.
// Recurrence per (b,c) row is strictly sequential in t (Heaviside spike);
// parallelism = B*C = 65536 rows = 1024 waves = structural.
//
// Round-2 lesson (kept): nt loads/stores avoid evicting the harness's dirty
// poison lines during our dispatch window (parasitic write-backs).
//
// Round-3 change: TT 64 -> 128. With TT=64 the kernel sweeps x/out 16 times
// at 256 B per 4 KiB row -- each pass touches every DRAM page for a single
// 256 B burst. Kernel sits at ~155 us vs the ~90 us two-stream floor with
// traffic already minimal and 0 bank conflicts => suspect DRAM page/activation
// overhead from the fine-grained strided sweep. TT=128 doubles the per-pass
// row chunk to 512 B and halves the pass count to 8.
//
// Cost: LDS 2 x 32 KB = 64 KB/block -> 2 blocks/CU (was 4). In-flight demand
// is still ample (512 resident waves x ~32 KB outstanding >> BW*latency).
//
// One wave (64 threads) per block, 64 rows/block. Double-buffered LDS tiles
// + TWO register prefetch buffers (2 x 128 VGPRs) -> 64 KB of global loads
// in flight per wave during compute.
//
// LDS swizzle (4-float groups, preserves b128, generalized to 32 groups):
//   slot(g, row) = (g & 16) | ((g & 15) ^ (row & 15))
//   idx(row, t)  = row*128 + slot(t>>2, row)*4 + (t & 3)
// Quarter-wave bank analysis: every b128 phase lands 2 lanes/bank (free).

#define LIF_BC 65536
#define LIF_T  1024
#define TT     128           // time-steps per tile (512 B per row per pass)
#define NT     (LIF_T / TT)  // 8 tiles
#define ROWS   64            // rows per block == wave size
#define GPT    (TT / 4)      // 32 4-float groups per row-tile

using fvec4 = __attribute__((ext_vector_type(4))) float;

__global__ __launch_bounds__(64) void lif_fwd(
    const float* __restrict__ x,
    const float* __restrict__ beta_p,
    const float* __restrict__ vth_p,
    float* __restrict__ out)
{
    __shared__ float lds0[ROWS * TT];   // 32 KB
    __shared__ float lds1[ROWS * TT];   // 32 KB

    const int lane = threadIdx.x;        // 0..63
    const int r0   = blockIdx.x * ROWS;  // first (b*C+c) row of this block

    const float beta = beta_p[0];
    const float vth  = vth_p[(r0 + lane) & 511];  // C = 512 (pow2)

    // load/store phase mapping: 2 rows per instr, 32 lanes x 16 B = 512 B/row
    const int l_row2 = lane >> 5;  // 0..1
    const int l_t    = lane & 31;  // 4-float group within row-tile

    fvec4 pf0[GPT], pf1[GPT];  // two tile-deep prefetch buffers (256 VGPRs)

    // 32 nt loads for tile `tile` (each instr: 2 rows x 512 B contiguous).
    auto issue_loads = [&](fvec4 (&pf)[GPT], int tile) {
#pragma unroll
        for (int j = 0; j < GPT; ++j) {
            const int row = 2 * j + l_row2;
            pf[j] = __builtin_nontemporal_load(
                (const fvec4*)&x[(size_t)(r0 + row) * LIF_T
                                 + (size_t)tile * TT + l_t * 4]);
        }
    };

    // Drain a prefetch buffer into an LDS tile (swizzled b128 writes).
    auto write_lds = [&](float* buf, fvec4 (&pf)[GPT]) {
#pragma unroll
        for (int j = 0; j < GPT; ++j) {
            const int row  = 2 * j + l_row2;
            const int slot = (l_t & 16) | ((l_t & 15) ^ (row & 15));
            *(fvec4*)&buf[row * TT + slot * 4] = pf[j];
        }
    };

    float mem = 0.0f, spk = 0.0f;

    // 128 recurrence steps for this lane's row; spikes overwrite LDS in place.
    // Bit-exact fp32 op order vs the numpy reference:
    //   rst = spk*Vth; mem = ((mem*beta) + x) - rst; spk = (mem - Vth) > 0.
    // __f*_rn blocks -ffp-contract FMA fusion (1-ulp drift flips a spike).
    auto compute = [&](float* buf) {
        const int rbase = lane * TT;
        const int sw    = lane & 15;
#pragma unroll
        for (int g = 0; g < GPT; ++g) {
            const int slot = (g & 16) | ((g & 15) ^ sw);
            fvec4 v = *(fvec4*)&buf[rbase + slot * 4];
#pragma unroll
            for (int e = 0; e < 4; ++e) {
                float rst = __fmul_rn(spk, vth);
                mem = __fsub_rn(__fadd_rn(__fmul_rn(mem, beta), v[e]), rst);
                spk = (__fsub_rn(mem, vth) > 0.0f) ? 1.0f : 0.0f;
                v[e] = spk;
            }
            *(fvec4*)&buf[rbase + slot * 4] = v;
        }
    };

    // Gather spikes from LDS and stream (nt) to global, coalesced (1 KiB/instr).
    auto store_tile = [&](const float* buf, int tile) {
#pragma unroll
        for (int j = 0; j < GPT; ++j) {
            const int row  = 2 * j + l_row2;
            const int slot = (l_t & 16) | ((l_t & 15) ^ (row & 15));
            fvec4 s = *(const fvec4*)&buf[row * TT + slot * 4];
            __builtin_nontemporal_store(
                s, (fvec4*)&out[(size_t)(r0 + row) * LIF_T
                                + (size_t)tile * TT + l_t * 4]);
        }
    };

    // ---- software pipeline: 2 tiles of loads in flight during compute ----
    issue_loads(pf0, 0);
    issue_loads(pf1, 1);
    write_lds(lds0, pf0);   // waits tile-0 loads (vmcnt issue-ordered)
    issue_loads(pf0, 2);

    for (int k = 0; k < NT; k += 2) {
        // even tile k (lds0 / pf0 side)
        compute(lds0);
        store_tile(lds0, k);                            // nt stores, fire & forget
        write_lds(lds1, pf1);                           // tile k+1 regs -> LDS
        if (k + 3 < NT) issue_loads(pf1, k + 3);
        // odd tile k+1 (lds1 / pf1 side)
        compute(lds1);
        store_tile(lds1, k + 1);
        if (k + 2 < NT) write_lds(lds0, pf0);           // tile k+2 regs -> LDS
        if (k + 4 < NT) issue_loads(pf0, k + 4);
    }
}

extern "C" void kernel_launch(void* const* d_in, const int* in_sizes, int n_in,
                              void* d_out, int out_size, void* d_ws, size_t ws_size,
                              hipStream_t stream) {
    const float* x    = (const float*)d_in[0];  // (B, C, T) fp32
    const float* beta = (const float*)d_in[1];  // scalar
    const float* vth  = (const float*)d_in[2];  // (C,) fp32
    float* out = (float*)d_out;                 // (B, C, T) fp32

    dim3 grid(LIF_BC / ROWS);                   // 1024 one-wave blocks
    lif_fwd<<<grid, 64, 0, stream>>>(x, beta, vth, out);
}

// Round 2
// 474.792 us; speedup vs baseline: 1.2486x; 1.2486x over previous
//
#include <hip/hip_runtime.h>

// Spiking LIF forward scan, LDS-staged + fully non-temporal global access.
//
// x: (B=128, C=512, T=1024) fp32, t contiguous. beta scalar, Vth per channel.
// Recurrence per (b,c) row is strictly sequential in t (Heaviside spike);
// parallelism = B*C = 65536 rows = 1024 waves (structural).
//
// Round-2 lesson (kept): nt loads/stores avoid evicting the harness's dirty
// poison lines during our dispatch window (parasitic write-backs).
//
// Round-4 post-mortem: TT=128 with TWO register prefetch buffers needed
// 256 VGPRs for pf alone -> VGPR_Count=256 (cap) + scratch spills
// (WRITE_SIZE 331 MB vs 268 ideal, BW 1.77 TB/s, occupancy 5%). The
// granularity experiment was confounded by the spill.
//
// Round-4 fix: keep TT=128 (512 B per row per pass, 8 passes -- the DRAM
// granularity theory under test) but:
//   * 1-deep register prefetch (pf[32] = 128 VGPRs). In-flight demand:
//     4 waves/CU x 32 KB = 32 MB device-wide >> BW*latency (~2.4 MB).
//   * SINGLE 32 KB LDS buffer. Within one wave, program order + the
//     in-order DS pipe make store(k) -> write_lds(k+1) on the same buffer
//     safe, and 32 KB/block restores 4 resident blocks/CU (1 wave/SIMD).
//
// Pipeline: compute(k) -> store(k) -> write_lds(k+1) [vmcnt wait covers
// loads issued one full compute earlier] -> issue_loads(k+2).
//
// LDS swizzle (4-float groups, preserves b128, 32 groups):
//   slot(g, row) = (g & 16) | ((g & 15) ^ (row & 15))
//   idx(row, t)  = row*128 + slot(t>>2, row)*4 + (t & 3)
// Quarter-wave bank analysis: every b128 phase lands 2 lanes/bank (free).

#define LIF_BC 65536
#define LIF_T  1024
#define TT     128           // time-steps per tile (512 B per row per pass)
#define NT     (LIF_T / TT)  // 8 tiles
#define ROWS   64            // rows per block == wave size
#define GPT    (TT / 4)      // 32 4-float groups per row-tile

using fvec4 = __attribute__((ext_vector_type(4))) float;

__global__ __launch_bounds__(64) void lif_fwd(
    const float* __restrict__ x,
    const float* __restrict__ beta_p,
    const float* __restrict__ vth_p,
    float* __restrict__ out)
{
    __shared__ float lds[ROWS * TT];     // 32 KB, single buffer

    const int lane = threadIdx.x;        // 0..63
    const int r0   = blockIdx.x * ROWS;  // first (b*C+c) row of this block

    const float beta = beta_p[0];
    const float vth  = vth_p[(r0 + lane) & 511];  // C = 512 (pow2)

    // load/store phase mapping: 2 rows per instr, 32 lanes x 16 B = 512 B/row
    const int l_row2 = lane >> 5;  // 0..1
    const int l_t    = lane & 31;  // 4-float group within row-tile

    fvec4 pf[GPT];  // ONE tile-deep prefetch buffer (128 VGPRs)

    // 32 nt loads for tile `tile` (each instr: 2 rows x 512 B contiguous).
    auto issue_loads = [&](int tile) {
#pragma unroll
        for (int j = 0; j < GPT; ++j) {
            const int row = 2 * j + l_row2;
            pf[j] = __builtin_nontemporal_load(
                (const fvec4*)&x[(size_t)(r0 + row) * LIF_T
                                 + (size_t)tile * TT + l_t * 4]);
        }
    };

    // Drain the prefetch buffer into the LDS tile (swizzled b128 writes).
    auto write_lds = [&]() {
#pragma unroll
        for (int j = 0; j < GPT; ++j) {
            const int row  = 2 * j + l_row2;
            const int slot = (l_t & 16) | ((l_t & 15) ^ (row & 15));
            *(fvec4*)&lds[row * TT + slot * 4] = pf[j];
        }
    };

    float mem = 0.0f, spk = 0.0f;

    // 128 recurrence steps for this lane's row; spikes overwrite LDS in place.
    // Bit-exact fp32 op order vs the numpy reference:
    //   rst = spk*Vth; mem = ((mem*beta) + x) - rst; spk = (mem - Vth) > 0.
    // __f*_rn blocks -ffp-contract FMA fusion (1-ulp drift flips a spike).
    auto compute = [&]() {
        const int rbase = lane * TT;
        const int sw    = lane & 15;
#pragma unroll
        for (int g = 0; g < GPT; ++g) {
            const int slot = (g & 16) | ((g & 15) ^ sw);
            fvec4 v = *(fvec4*)&lds[rbase + slot * 4];
#pragma unroll
            for (int e = 0; e < 4; ++e) {
                float rst = __fmul_rn(spk, vth);
                mem = __fsub_rn(__fadd_rn(__fmul_rn(mem, beta), v[e]), rst);
                spk = (__fsub_rn(mem, vth) > 0.0f) ? 1.0f : 0.0f;
                v[e] = spk;
            }
            *(fvec4*)&lds[rbase + slot * 4] = v;
        }
    };

    // Gather spikes from LDS and stream (nt) to global, coalesced (1 KiB/instr).
    auto store_tile = [&](int tile) {
#pragma unroll
        for (int j = 0; j < GPT; ++j) {
            const int row  = 2 * j + l_row2;
            const int slot = (l_t & 16) | ((l_t & 15) ^ (row & 15));
            fvec4 s = *(const fvec4*)&lds[row * TT + slot * 4];
            __builtin_nontemporal_store(
                s, (fvec4*)&out[(size_t)(r0 + row) * LIF_T
                                + (size_t)tile * TT + l_t * 4]);
        }
    };

    // ---- software pipeline: 1 tile of loads in flight during compute ----
    issue_loads(0);
    write_lds();        // waits tile-0 loads (vmcnt issue-ordered), once
    issue_loads(1);     // in flight during compute(0)

    for (int k = 0; k < NT; ++k) {
        compute();                      // recurrence on tile k (in LDS)
        store_tile(k);                  // nt stores, fire & forget
        if (k + 1 < NT) write_lds();    // regs -> LDS (waits tile-k+1 loads;
                                        //   DS pipe orders after store reads)
        if (k + 2 < NT) issue_loads(k + 2);  // in flight during compute(k+1)
    }
}

extern "C" void kernel_launch(void* const* d_in, const int* in_sizes, int n_in,
                              void* d_out, int out_size, void* d_ws, size_t ws_size,
                              hipStream_t stream) {
    const float* x    = (const float*)d_in[0];  // (B, C, T) fp32
    const float* beta = (const float*)d_in[1];  // scalar
    const float* vth  = (const float*)d_in[2];  // (C,) fp32
    float* out = (float*)d_out;                 // (B, C, T) fp32

    dim3 grid(LIF_BC / ROWS);                   // 1024 one-wave blocks
    lif_fwd<<<grid, 64, 0, stream>>>(x, beta, vth, out);
}

// Round 3
// 466.600 us; speedup vs baseline: 1.2705x; 1.0176x over previous
//
#include <hip/hip_runtime.h>

// Spiking LIF forward scan, LDS-staged + fully non-temporal global access.
//
// x: (B=128, C=512, T=1024) fp32, t contiguous. beta scalar, Vth per channel.
// Recurrence per (b,c) row is strictly sequential in t (Heaviside spike);
// parallelism = B*C = 65536 rows (structural).
//
// Round-5 theory: kernel ran ~154 us at only ~2.6 TB/s (fills hit 6.4) with
// minimal traffic, 0 bank conflicts, no spills, ample outstanding loads.
// Remaining suspects both point at DRAM presentation:
//   (a) sub-page chunks: 512 B per 4 KiB row per pass < HBM3E ~1 KiB page
//       -> one activation per half-page chunk (explains 256->512 B being flat);
//   (b) fine-grained R/W turnaround across ~1000 strided streams.
// Fix: 16 rows/block, CHUNK = 256 floats = 1 KiB per row per phase. Every
// load/store instruction is now ONE contiguous 1 KiB line of ONE row (64
// lanes x 16 B). 4 phases over T=1024.
//
// Side benefits: LDS 16 KB/block -> 10 blocks/CU resident (was 4);
// pf[16] = 64 VGPRs (vs 128) -> zero spill risk.
// Cost: compute uses 16/64 lanes; total VALU issue ~20 us device-wide,
// far under the ~85 us memory floor, and 2.5 waves/SIMD interleave the
// serial dependency chains.
//
// nt loads/stores kept (round-2 lesson): no-allocate accesses leave the
// harness's dirty poison lines cached -> no parasitic write-backs.
//
// LDS swizzle: element (row, slot s) stored at lds[row*256 + (s ^ row)*4].
// Every DS phase (write_lds per-row b128, compute per-lane-row b128, store
// gather) lands 2 lanes/bank per quarter-wave = the free floor.

#define LIF_BC 65536
#define LIF_T  1024
#define CHUNK  256           // floats per row per phase = 1 KiB
#define NP     (LIF_T / CHUNK)  // 4 phases
#define ROWS   16            // rows per block (one wave)
#define JPT    ROWS          // one 1 KiB load/store instr per row per phase

using fvec4 = __attribute__((ext_vector_type(4))) float;

__global__ __launch_bounds__(64) void lif_fwd(
    const float* __restrict__ x,
    const float* __restrict__ beta_p,
    const float* __restrict__ vth_p,
    float* __restrict__ out)
{
    __shared__ float lds[ROWS * CHUNK];  // 16 KB, single buffer

    const int lane = threadIdx.x;        // 0..63
    const int r0   = blockIdx.x * ROWS;  // first (b*C+c) row of this block

    const float beta = beta_p[0];
    const float vth  = vth_p[(r0 + lane) & 511];  // C = 512 (pow2)

    fvec4 pf[JPT];  // one phase of prefetch: 16 rows x 1 KiB -> 64 VGPRs

    // 16 nt loads; instr j = one contiguous 1 KiB line of row r0+j.
    auto issue_loads = [&](int ph) {
#pragma unroll
        for (int j = 0; j < JPT; ++j) {
            pf[j] = __builtin_nontemporal_load(
                (const fvec4*)&x[(size_t)(r0 + j) * LIF_T
                                 + (size_t)ph * CHUNK + lane * 4]);
        }
    };

    // Drain prefetch regs into LDS (swizzled b128 writes, 2-way free).
    auto write_lds = [&]() {
#pragma unroll
        for (int j = 0; j < JPT; ++j) {
            const int slot = lane ^ j;   // j < 16: permutes slots 0..63
            *(fvec4*)&lds[j * CHUNK + slot * 4] = pf[j];
        }
    };

    float mem = 0.0f, spk = 0.0f;

    // 256 recurrence steps for lane's row (lanes 0..15 active); spikes
    // overwrite LDS in place. Bit-exact fp32 op order vs the reference:
    //   rst = spk*Vth; mem = ((mem*beta) + x) - rst; spk = (mem - Vth) > 0.
    // __f*_rn blocks -ffp-contract FMA fusion (1-ulp drift flips a spike).
    auto compute = [&]() {
        if (lane < ROWS) {
            const int rbase = lane * CHUNK;
            const int sw    = lane;      // row == lane
#pragma unroll
            for (int g = 0; g < CHUNK / 4; ++g) {
                const int slot = g ^ sw;
                fvec4 v = *(fvec4*)&lds[rbase + slot * 4];
#pragma unroll
                for (int e = 0; e < 4; ++e) {
                    float rst = __fmul_rn(spk, vth);
                    mem = __fsub_rn(__fadd_rn(__fmul_rn(mem, beta), v[e]), rst);
                    spk = (__fsub_rn(mem, vth) > 0.0f) ? 1.0f : 0.0f;
                    v[e] = spk;
                }
                *(fvec4*)&lds[rbase + slot * 4] = v;
            }
        }
    };

    // Gather spikes from LDS, stream (nt) to global: 1 KiB contiguous/instr.
    auto store_tile = [&](int ph) {
#pragma unroll
        for (int j = 0; j < JPT; ++j) {
            const int slot = lane ^ j;
            fvec4 s = *(const fvec4*)&lds[j * CHUNK + slot * 4];
            __builtin_nontemporal_store(
                s, (fvec4*)&out[(size_t)(r0 + j) * LIF_T
                                + (size_t)ph * CHUNK + lane * 4]);
        }
    };

    // ---- software pipeline: 1 phase of loads in flight during compute ----
    issue_loads(0);
    write_lds();        // waits phase-0 loads (vmcnt issue-ordered), once
    issue_loads(1);     // in flight during compute(0)

    for (int k = 0; k < NP; ++k) {
        compute();                      // recurrence on phase k (in LDS)
        store_tile(k);                  // nt stores, fire & forget
        if (k + 1 < NP) write_lds();    // regs -> LDS (waits phase-k+1 loads;
                                        //   in-order DS pipe orders after the
                                        //   store gather reads)
        if (k + 2 < NP) issue_loads(k + 2);  // in flight during compute(k+1)
    }
}

extern "C" void kernel_launch(void* const* d_in, const int* in_sizes, int n_in,
                              void* d_out, int out_size, void* d_ws, size_t ws_size,
                              hipStream_t stream) {
    const float* x    = (const float*)d_in[0];  // (B, C, T) fp32
    const float* beta = (const float*)d_in[1];  // scalar
    const float* vth  = (const float*)d_in[2];  // (C,) fp32
    float* out = (float*)d_out;                 // (B, C, T) fp32

    dim3 grid(LIF_BC / ROWS);                   // 4096 one-wave blocks
    lif_fwd<<<grid, 64, 0, stream>>>(x, beta, vth, out);
}